// Round 7
// baseline (187.688 us; speedup 1.0000x reference)
//
#include <hip/hip_runtime.h>
#include <math.h>

#define BB 64
#define TT 2048
#define RNN 1024
#define EMB 512
#define ATTN 128
#define NF 32
#define KS 31
#define PADW 15

#define CHW 16            // t per wave (energy chunk; ms granularity)
#define NCH (TT / CHW)    // 128 chunks per b
#define BLK_T 64          // t per energy block (4 waves)

#define SEG_T 64          // t per ctx segment
#define NSEG (TT / SEG_T) // 32
#define NPART (NSEG * 2)  // 64 partials (2 t-parities per segment)

__device__ __forceinline__ float fast_tanh(float x) {
    float ax = fabsf(x);
    float e = __expf(-2.f * ax);
    float r = (1.f - e) * __builtin_amdgcn_rcpf(1.f + e);
    return copysignf(r, x);
}

// ---------------------------------------------------------------------------
// Kernel 1: pq[b][a] = sum_r h[b][r] * Wq[a][r]
// ---------------------------------------------------------------------------
__global__ __launch_bounds__(256) void pq_kernel(const float* __restrict__ h,
                                                 const float* __restrict__ Wq,
                                                 float* __restrict__ pq) {
    int b = blockIdx.x >> 2;
    int q = blockIdx.x & 3;
    __shared__ float s_h[RNN];
    for (int i = threadIdx.x; i < RNN; i += 256) s_h[i] = h[b * RNN + i];
    __syncthreads();

    int wave = threadIdx.x >> 6;
    int lane = threadIdx.x & 63;
#pragma unroll 2
    for (int j = 0; j < 8; ++j) {
        int a = q * 32 + wave * 8 + j;
        const float4* wq4 = (const float4*)(Wq + (size_t)a * RNN);
        float acc = 0.f;
#pragma unroll
        for (int i = 0; i < 4; ++i) {
            float4 w4 = wq4[lane + 64 * i];
            float4 h4 = *(const float4*)(s_h + 4 * (lane + 64 * i));
            acc += w4.x * h4.x + w4.y * h4.y + w4.z * h4.z + w4.w * h4.w;
        }
#pragma unroll
        for (int off = 32; off > 0; off >>= 1) acc += __shfl_xor(acc, off, 64);
        if (lane == 0) pq[b * ATTN + a] = acc;
    }
}

// ---------------------------------------------------------------------------
// Kernel 2: energies -> per-16t-chunk (m, s) and unnormalized p (wp).
// R6 wave-autonomous structure WITHOUT the ctx tail (register diet).
// grid = B * 32 = 2048, block = 256 (4 waves x 16 t)
// ---------------------------------------------------------------------------
__global__ __launch_bounds__(256) void energy_kernel(
    const float* __restrict__ pm,     // [B][T][ATTN]
    const float* __restrict__ awc,    // [B][2][T]
    const unsigned char* __restrict__ mask,  // [B][T]
    const float* __restrict__ pq,     // [B][ATTN]
    const float* __restrict__ Wconv,  // [NF][2][KS]
    const float* __restrict__ Wloc,   // [ATTN][NF]
    const float* __restrict__ Wv,     // [ATTN]
    float* __restrict__ wp,           // [B][T] unnormalized exp
    float* __restrict__ ms)           // [B][NCH][2] (m, s)
{
    int b = blockIdx.x >> 5;
    int chg = blockIdx.x & 31;
    int t0b = chg * BLK_T;
    int tid = threadIdx.x;
    int w = tid >> 6;
    int lane = tid & 63;
    int ch = chg * 4 + w;
    int t0w = ch * CHW;

    __shared__ float s_awc[2][BLK_T + 2 * PADW + 2];
    __shared__ float s_conv[BLK_T][36];

    for (int i = tid; i < 2 * (BLK_T + 2 * PADW); i += 256) {
        int c = i / (BLK_T + 2 * PADW);
        int j = i % (BLK_T + 2 * PADW);
        int tg = t0b - PADW + j;
        s_awc[c][j] = (tg >= 0 && tg < TT) ? awc[((size_t)b * 2 + c) * TT + tg] : 0.f;
    }
    __syncthreads();

    {
        int t = tid & 63;
        float aw[2][KS];
#pragma unroll
        for (int c = 0; c < 2; ++c)
#pragma unroll
            for (int k = 0; k < KS; ++k) aw[c][k] = s_awc[c][t + k];
#pragma unroll
        for (int ff = 0; ff < 8; ++ff) {
            int f = w * 8 + ff;  // wave-uniform -> scalar Wconv loads
            float acc = 0.f;
#pragma unroll
            for (int c = 0; c < 2; ++c)
#pragma unroll
                for (int k = 0; k < KS; ++k)
                    acc += aw[c][k] * Wconv[(f * 2 + c) * KS + k];
            s_conv[t][f] = acc;
        }
    }
    __syncthreads();  // only barrier

    float wl0[NF], wl1[NF];
#pragma unroll
    for (int f = 0; f < NF; ++f) {
        wl0[f] = Wloc[lane * NF + f];
        wl1[f] = Wloc[(lane + 64) * NF + f];
    }
    float pq0 = pq[b * ATTN + lane], pq1 = pq[b * ATTN + lane + 64];
    float wv0 = Wv[lane], wv1 = Wv[lane + 64];

    float e[CHW];
#pragma unroll
    for (int h = 0; h < 2; ++h) {
        float pA[8], pB[8];
#pragma unroll
        for (int i = 0; i < 8; ++i) {
            const float* r = pm + ((size_t)b * TT + t0w + h * 8 + i) * ATTN;
            pA[i] = r[lane];
            pB[i] = r[lane + 64];
        }
#pragma unroll
        for (int i = 0; i < 8; ++i) {
            int tl = w * CHW + h * 8 + i;
            float v0 = pq0 + pA[i], v1 = pq1 + pB[i];
            const float4* cv4 = (const float4*)&s_conv[tl][0];
#pragma unroll
            for (int f4 = 0; f4 < 8; ++f4) {
                float4 cv = cv4[f4];
                v0 += cv.x * wl0[f4 * 4 + 0] + cv.y * wl0[f4 * 4 + 1] +
                      cv.z * wl0[f4 * 4 + 2] + cv.w * wl0[f4 * 4 + 3];
                v1 += cv.x * wl1[f4 * 4 + 0] + cv.y * wl1[f4 * 4 + 1] +
                      cv.z * wl1[f4 * 4 + 2] + cv.w * wl1[f4 * 4 + 3];
            }
            e[h * 8 + i] = wv0 * fast_tanh(v0) + wv1 * fast_tanh(v1);
        }
    }

    // batched butterfly: 6 rounds x 16 independent shuffles
#pragma unroll
    for (int off = 32; off > 0; off >>= 1)
#pragma unroll
        for (int i = 0; i < CHW; ++i) e[i] += __shfl_xor(e[i], off, 64);

    // mask (word loads, identical in every lane)
    {
        const unsigned int* mk4 = (const unsigned int*)(mask + (size_t)b * TT + t0w);
#pragma unroll
        for (int q = 0; q < 4; ++q) {
            unsigned int mword = mk4[q];
#pragma unroll
            for (int j = 0; j < 4; ++j)
                if ((mword >> (8 * j)) & 0xff) e[q * 4 + j] = -1e30f;
        }
    }

    // in-register chunk softmax (redundant per lane)
    float m = e[0];
#pragma unroll
    for (int i = 1; i < CHW; ++i) m = fmaxf(m, e[i]);
    float s = 0.f;
#pragma unroll
    for (int i = 0; i < CHW; ++i) {
        e[i] = __expf(e[i] - m);  // p overwrites e (register diet)
        s += e[i];
    }
    if (lane == 0) {
        ms[((size_t)b * NCH + ch) * 2 + 0] = m;
        ms[((size_t)b * NCH + ch) * 2 + 1] = s;
    }
    {
        float pv = e[0];
#pragma unroll
        for (int i = 1; i < CHW; ++i)
            if (lane == i) pv = e[i];
        if (lane < CHW) wp[(size_t)b * TT + t0w + lane] = pv;
    }
}

// ---------------------------------------------------------------------------
// Kernel 3: scales. grid = B, block = 256.
//   M = max m_c, S = sum s_c exp(m_c-M); wts[t] = wp[t]*exp(m_{ch(t)}-M)/S
// wts goes straight to d_out (final attention weights).
// ---------------------------------------------------------------------------
__global__ __launch_bounds__(256) void scales_kernel(
    const float* __restrict__ wp, const float* __restrict__ ms,
    float* __restrict__ wts) {
    int b = blockIdx.x;
    int tid = threadIdx.x;
    __shared__ float s_m[NCH], s_s[NCH], s_scale[NCH];
    if (tid < NCH) {
        s_m[tid] = ms[((size_t)b * NCH + tid) * 2 + 0];
        s_s[tid] = ms[((size_t)b * NCH + tid) * 2 + 1];
    }
    __syncthreads();
    float M = -1e30f;
#pragma unroll 8
    for (int c = 0; c < NCH; ++c) M = fmaxf(M, s_m[c]);
    float S = 0.f;
#pragma unroll 8
    for (int c = 0; c < NCH; ++c) S += s_s[c] * __expf(s_m[c] - M);
    float invS = 1.f / S;
    if (tid < NCH) s_scale[tid] = __expf(s_m[tid] - M) * invS;
    __syncthreads();
#pragma unroll
    for (int i = 0; i < 8; ++i) {
        int t = i * 256 + tid;
        wts[(size_t)b * TT + t] = wp[(size_t)b * TT + t] * s_scale[t >> 4];
    }
}

// ---------------------------------------------------------------------------
// Kernel 4: ctx partials from FINAL weights. grid = B*NSEG = 2048, block 256.
// thread = (e4 = tid&127, t-parity = tid>>7); float4 streaming. Tiny VGPR.
// ---------------------------------------------------------------------------
__global__ __launch_bounds__(256) void ctx_partial_kernel(
    const float* __restrict__ mem,  // [B][T][EMB]
    const float* __restrict__ wts,  // [B][T] final weights
    float* __restrict__ partial)    // [NPART][B][EMB]
{
    int b = blockIdx.x >> 5;
    int seg = blockIdx.x & 31;
    int tid = threadIdx.x;
    int e4 = tid & 127;
    int half = tid >> 7;

    __shared__ float s_w[SEG_T];
    if (tid < SEG_T) s_w[tid] = wts[(size_t)b * TT + seg * SEG_T + tid];
    __syncthreads();

    float4 acc = {0.f, 0.f, 0.f, 0.f};
    const float4* m4 = (const float4*)(mem + ((size_t)b * TT + seg * SEG_T) * EMB) +
                       (size_t)half * (EMB / 4) + e4;
#pragma unroll 8
    for (int i = 0; i < SEG_T / 2; ++i) {
        float wv = s_w[2 * i + half];
        float4 mv = m4[(size_t)i * (2 * EMB / 4)];
        acc.x += wv * mv.x;
        acc.y += wv * mv.y;
        acc.z += wv * mv.z;
        acc.w += wv * mv.w;
    }
    float4* p4 = (float4*)(partial + ((size_t)(seg * 2 + half) * BB + b) * EMB) + e4;
    *p4 = acc;
}

// ---------------------------------------------------------------------------
// Kernel 5: reduce 64 partials -> ctx. grid = B*EMB/256 = 128, block 256.
// ---------------------------------------------------------------------------
__global__ __launch_bounds__(256) void ctx_reduce_kernel(
    const float* __restrict__ partial, float* __restrict__ ctx) {
    int idx = blockIdx.x * 256 + threadIdx.x;  // 0 .. B*EMB-1
    float acc = 0.f;
#pragma unroll 8
    for (int s = 0; s < NPART; ++s) acc += partial[(size_t)s * (BB * EMB) + idx];
    ctx[idx] = acc;
}

// ---------------------------------------------------------------------------
extern "C" void kernel_launch(void* const* d_in, const int* in_sizes, int n_in,
                              void* d_out, int out_size, void* d_ws, size_t ws_size,
                              hipStream_t stream) {
    const float* h    = (const float*)d_in[0];
    const float* mem  = (const float*)d_in[1];
    const float* pmem = (const float*)d_in[2];
    const float* awc  = (const float*)d_in[3];
    const unsigned char* mask = (const unsigned char*)d_in[4];
    const float* Wq   = (const float*)d_in[5];
    const float* Wcv  = (const float*)d_in[6];
    const float* Wloc = (const float*)d_in[7];
    const float* Wv   = (const float*)d_in[8];

    float* out = (float*)d_out;
    float* ctx = out;             // [B][EMB]
    float* wts = out + BB * EMB;  // [B][T]

    float* ws = (float*)d_ws;
    float* pq = ws;                 // [B][ATTN]
    float* wp = pq + BB * ATTN;     // [B][T]
    float* ms = wp + BB * TT;       // [B][NCH][2]
    float* partial = ms + BB * NCH * 2;  // [NPART][B][EMB]

    pq_kernel<<<BB * 4, 256, 0, stream>>>(h, Wq, pq);
    energy_kernel<<<BB * 32, 256, 0, stream>>>(pmem, awc, mask, pq, Wcv, Wloc,
                                               Wv, wp, ms);
    scales_kernel<<<BB, 256, 0, stream>>>(wp, ms, wts);
    ctx_partial_kernel<<<BB * NSEG, 256, 0, stream>>>(mem, wts, partial);
    ctx_reduce_kernel<<<(BB * EMB) / 256, 256, 0, stream>>>(partial, ctx);
}

// Round 8
// 147.400 us; speedup vs baseline: 1.2733x; 1.2733x over previous
//
#include <hip/hip_runtime.h>
#include <math.h>

#define BB 64
#define TT 2048
#define RNN 1024
#define EMB 512
#define ATTN 128
#define NF 32
#define KS 31
#define PADW 15

#define CHUNK 64          // energy t-chunk per block; ms granularity
#define NCH (TT / CHUNK)  // 32

#define SEG_T 64          // t per ctx segment
#define NSEG (TT / SEG_T) // 32
#define NPART (NSEG * 2)  // 64 partials

__device__ __forceinline__ float fast_tanh(float x) {
    float ax = fabsf(x);
    float e = __expf(-2.f * ax);
    float r = (1.f - e) * __builtin_amdgcn_rcpf(1.f + e);
    return copysignf(r, x);
}

// ---------------------------------------------------------------------------
// Kernel 1: pq[b][a] = sum_r h[b][r] * Wq[a][r]
// ---------------------------------------------------------------------------
__global__ __launch_bounds__(256) void pq_kernel(const float* __restrict__ h,
                                                 const float* __restrict__ Wq,
                                                 float* __restrict__ pq) {
    int b = blockIdx.x >> 2;
    int q = blockIdx.x & 3;
    __shared__ float s_h[RNN];
    for (int i = threadIdx.x; i < RNN; i += 256) s_h[i] = h[b * RNN + i];
    __syncthreads();

    int wave = threadIdx.x >> 6;
    int lane = threadIdx.x & 63;
#pragma unroll 2
    for (int j = 0; j < 8; ++j) {
        int a = q * 32 + wave * 8 + j;
        const float4* wq4 = (const float4*)(Wq + (size_t)a * RNN);
        float acc = 0.f;
#pragma unroll
        for (int i = 0; i < 4; ++i) {
            float4 w4 = wq4[lane + 64 * i];
            float4 h4 = *(const float4*)(s_h + 4 * (lane + 64 * i));
            acc += w4.x * h4.x + w4.y * h4.y + w4.z * h4.z + w4.w * h4.w;
        }
#pragma unroll
        for (int off = 32; off > 0; off >>= 1) acc += __shfl_xor(acc, off, 64);
        if (lane == 0) pq[b * ATTN + a] = acc;
    }
}

// ---------------------------------------------------------------------------
// Kernel 2: energy — R4's proven structure WITHOUT the ctx tail.
// grid = B * NCH = 2048, block = 256 (wave owns 16 t; serial shuffle reduce)
// ---------------------------------------------------------------------------
__global__ __launch_bounds__(256) void energy_kernel(
    const float* __restrict__ pm,     // [B][T][ATTN]
    const float* __restrict__ awc,    // [B][2][T]
    const unsigned char* __restrict__ mask,  // [B][T]
    const float* __restrict__ pq,     // [B][ATTN]
    const float* __restrict__ Wconv,  // [NF][2][KS]
    const float* __restrict__ Wloc,   // [ATTN][NF]
    const float* __restrict__ Wv,     // [ATTN]
    float* __restrict__ wp,           // [B][T] unnormalized exp
    float* __restrict__ ms)           // [B][NCH][2] (m, s)
{
    int b = blockIdx.x >> 5;
    int ch = blockIdx.x & 31;
    int t0 = ch * CHUNK;
    int tid = threadIdx.x;

    __shared__ float s_awc[2][CHUNK + 2 * PADW];  // 2 x 94
    __shared__ float s_conv[CHUNK][36];
    __shared__ float s_e[CHUNK];
    __shared__ float s_p[CHUNK];

    for (int i = tid; i < 2 * (CHUNK + 2 * PADW); i += 256) {
        int c = i / (CHUNK + 2 * PADW);
        int j = i % (CHUNK + 2 * PADW);
        int tg = t0 - PADW + j;
        s_awc[c][j] = (tg >= 0 && tg < TT) ? awc[((size_t)b * 2 + c) * TT + tg] : 0.f;
    }
    __syncthreads();

    // conv: thread = (t = tid&63, filter-group = tid>>6), wave-uniform f
    {
        int t = tid & 63;
        int fh = tid >> 6;
        float aw[2][KS];
#pragma unroll
        for (int c = 0; c < 2; ++c)
#pragma unroll
            for (int k = 0; k < KS; ++k) aw[c][k] = s_awc[c][t + k];
#pragma unroll
        for (int ff = 0; ff < 8; ++ff) {
            int f = fh * 8 + ff;  // wave-uniform -> scalar Wconv loads
            float acc = 0.f;
#pragma unroll
            for (int c = 0; c < 2; ++c)
#pragma unroll
                for (int k = 0; k < KS; ++k)
                    acc += aw[c][k] * Wconv[(f * 2 + c) * KS + k];
            s_conv[t][f] = acc;
        }
    }
    __syncthreads();

    // energies: wave owns 16 t, lane owns attn dims (lane, lane+64)
    int wave = tid >> 6;
    int lane = tid & 63;

    float wl0[NF], wl1[NF];
#pragma unroll
    for (int f = 0; f < NF; ++f) {
        wl0[f] = Wloc[lane * NF + f];
        wl1[f] = Wloc[(lane + 64) * NF + f];
    }
    float pq0 = pq[b * ATTN + lane], pq1 = pq[b * ATTN + lane + 64];
    float wv0 = Wv[lane], wv1 = Wv[lane + 64];

    float eout = 0.f;
#pragma unroll 2
    for (int i = 0; i < 16; ++i) {
        int tl = wave * 16 + i;
        int tg = t0 + tl;
        float v0 = pq0, v1 = pq1;
        const float4* cv4 = (const float4*)&s_conv[tl][0];  // uniform broadcast
#pragma unroll
        for (int f4 = 0; f4 < 8; ++f4) {
            float4 cv = cv4[f4];
            v0 += cv.x * wl0[f4 * 4 + 0] + cv.y * wl0[f4 * 4 + 1] +
                  cv.z * wl0[f4 * 4 + 2] + cv.w * wl0[f4 * 4 + 3];
            v1 += cv.x * wl1[f4 * 4 + 0] + cv.y * wl1[f4 * 4 + 1] +
                  cv.z * wl1[f4 * 4 + 2] + cv.w * wl1[f4 * 4 + 3];
        }
        const float* pmrow = pm + ((size_t)(b * TT + tg)) * ATTN;
        v0 += pmrow[lane];
        v1 += pmrow[lane + 64];
        float e = wv0 * fast_tanh(v0) + wv1 * fast_tanh(v1);
#pragma unroll
        for (int off = 32; off > 0; off >>= 1) e += __shfl_xor(e, off, 64);
        if (lane == i) eout = e;  // butterfly leaves sum in all lanes
    }
    if (lane < 16) {
        int tl = wave * 16 + lane;
        float e = eout;
        if (mask[(size_t)b * TT + t0 + tl] != 0) e = -1e30f;
        s_e[tl] = e;
    }
    __syncthreads();

    // chunk max over 64 (redundant per wave)
    float m = s_e[lane];
#pragma unroll
    for (int off = 32; off > 0; off >>= 1) m = fmaxf(m, __shfl_xor(m, off, 64));

    if (tid < CHUNK) {
        float p = __expf(s_e[tid] - m);
        s_p[tid] = p;
        wp[(size_t)b * TT + t0 + tid] = p;
    }
    __syncthreads();

    float ssum = s_p[lane];
#pragma unroll
    for (int off = 32; off > 0; off >>= 1) ssum += __shfl_xor(ssum, off, 64);
    if (tid == 0) {
        ms[((size_t)b * NCH + ch) * 2 + 0] = m;
        ms[((size_t)b * NCH + ch) * 2 + 1] = ssum;
    }
}

// ---------------------------------------------------------------------------
// Kernel 3: scales. grid = B, block = 256.
//   M = max m_c, S = sum s_c exp(m_c-M); wts[t] = wp[t]*exp(m_{ch(t)}-M)/S
// ---------------------------------------------------------------------------
__global__ __launch_bounds__(256) void scales_kernel(
    const float* __restrict__ wp, const float* __restrict__ ms,
    float* __restrict__ wts) {
    int b = blockIdx.x;
    int tid = threadIdx.x;
    __shared__ float s_m[NCH], s_s[NCH], s_scale[NCH];
    if (tid < NCH) {
        s_m[tid] = ms[((size_t)b * NCH + tid) * 2 + 0];
        s_s[tid] = ms[((size_t)b * NCH + tid) * 2 + 1];
    }
    __syncthreads();
    float M = -1e30f;
#pragma unroll 8
    for (int c = 0; c < NCH; ++c) M = fmaxf(M, s_m[c]);
    float S = 0.f;
#pragma unroll 8
    for (int c = 0; c < NCH; ++c) S += s_s[c] * __expf(s_m[c] - M);
    float invS = 1.f / S;
    if (tid < NCH) s_scale[tid] = __expf(s_m[tid] - M) * invS;
    __syncthreads();
#pragma unroll
    for (int i = 0; i < 8; ++i) {
        int t = i * 256 + tid;
        wts[(size_t)b * TT + t] = wp[(size_t)b * TT + t] * s_scale[t >> 6];
    }
}

// ---------------------------------------------------------------------------
// Kernel 4: ctx partials from FINAL weights. grid = B*NSEG = 2048, block 256.
// thread = (e4 = tid&127, t-parity = tid>>7); float4 streaming. Tiny VGPR.
// ---------------------------------------------------------------------------
__global__ __launch_bounds__(256) void ctx_partial_kernel(
    const float* __restrict__ mem,  // [B][T][EMB]
    const float* __restrict__ wts,  // [B][T] final weights
    float* __restrict__ partial)    // [NPART][B][EMB]
{
    int b = blockIdx.x >> 5;
    int seg = blockIdx.x & 31;
    int tid = threadIdx.x;
    int e4 = tid & 127;
    int half = tid >> 7;

    __shared__ float s_w[SEG_T];
    if (tid < SEG_T) s_w[tid] = wts[(size_t)b * TT + seg * SEG_T + tid];
    __syncthreads();

    float4 acc = {0.f, 0.f, 0.f, 0.f};
    const float4* m4 = (const float4*)(mem + ((size_t)b * TT + seg * SEG_T) * EMB) +
                       (size_t)half * (EMB / 4) + e4;
#pragma unroll 8
    for (int i = 0; i < SEG_T / 2; ++i) {
        float wv = s_w[2 * i + half];
        float4 mv = m4[(size_t)i * (2 * EMB / 4)];
        acc.x += wv * mv.x;
        acc.y += wv * mv.y;
        acc.z += wv * mv.z;
        acc.w += wv * mv.w;
    }
    float4* p4 = (float4*)(partial + ((size_t)(seg * 2 + half) * BB + b) * EMB) + e4;
    *p4 = acc;
}

// ---------------------------------------------------------------------------
// Kernel 5: reduce 64 partials -> ctx. grid = B*EMB/256 = 128, block 256.
// ---------------------------------------------------------------------------
__global__ __launch_bounds__(256) void ctx_reduce_kernel(
    const float* __restrict__ partial, float* __restrict__ ctx) {
    int idx = blockIdx.x * 256 + threadIdx.x;  // 0 .. B*EMB-1
    float acc = 0.f;
#pragma unroll 8
    for (int s = 0; s < NPART; ++s) acc += partial[(size_t)s * (BB * EMB) + idx];
    ctx[idx] = acc;
}

// ---------------------------------------------------------------------------
extern "C" void kernel_launch(void* const* d_in, const int* in_sizes, int n_in,
                              void* d_out, int out_size, void* d_ws, size_t ws_size,
                              hipStream_t stream) {
    const float* h    = (const float*)d_in[0];
    const float* mem  = (const float*)d_in[1];
    const float* pmem = (const float*)d_in[2];
    const float* awc  = (const float*)d_in[3];
    const unsigned char* mask = (const unsigned char*)d_in[4];
    const float* Wq   = (const float*)d_in[5];
    const float* Wcv  = (const float*)d_in[6];
    const float* Wloc = (const float*)d_in[7];
    const float* Wv   = (const float*)d_in[8];

    float* out = (float*)d_out;
    float* ctx = out;             // [B][EMB]
    float* wts = out + BB * EMB;  // [B][T]

    float* ws = (float*)d_ws;
    float* pq = ws;                      // [B][ATTN]
    float* wp = pq + BB * ATTN;          // [B][T]
    float* ms = wp + BB * TT;            // [B][NCH][2]
    float* partial = ms + BB * NCH * 2;  // [NPART][B][EMB]

    pq_kernel<<<BB * 4, 256, 0, stream>>>(h, Wq, pq);
    energy_kernel<<<BB * NCH, 256, 0, stream>>>(pmem, awc, mask, pq, Wcv, Wloc,
                                                Wv, wp, ms);
    scales_kernel<<<BB, 256, 0, stream>>>(wp, ms, wts);
    ctx_partial_kernel<<<BB * NSEG, 256, 0, stream>>>(mem, wts, partial);
    ctx_reduce_kernel<<<(BB * EMB) / 256, 256, 0, stream>>>(partial, ctx);
}

// Round 9
// 129.725 us; speedup vs baseline: 1.4468x; 1.1362x over previous
//
#include <hip/hip_runtime.h>
#include <math.h>

#define BB 64
#define TT 2048
#define RNN 1024
#define EMB 512
#define ATTN 128
#define NF 32
#define KS 31
#define PADW 15

#define TCHK_BLK 128        // t per block (4 waves)
#define TCHK_W 32           // t per wave
#define NCH (TT / TCHK_W)   // 64 chunks per b (ms granularity)

__device__ __forceinline__ float fast_tanh(float x) {
    float ax = fabsf(x);
    float e = __expf(-2.f * ax);
    float r = (1.f - e) * __builtin_amdgcn_rcpf(1.f + e);
    return copysignf(r, x);
}

// ---------------------------------------------------------------------------
// Kernel 1: pq[b][a] = sum_r h[b][r] * Wq[a][r]
// ---------------------------------------------------------------------------
__global__ __launch_bounds__(256) void pq_kernel(const float* __restrict__ h,
                                                 const float* __restrict__ Wq,
                                                 float* __restrict__ pq) {
    int b = blockIdx.x >> 2;
    int q = blockIdx.x & 3;
    __shared__ float s_h[RNN];
    for (int i = threadIdx.x; i < RNN; i += 256) s_h[i] = h[b * RNN + i];
    __syncthreads();

    int wave = threadIdx.x >> 6;
    int lane = threadIdx.x & 63;
#pragma unroll 2
    for (int j = 0; j < 8; ++j) {
        int a = q * 32 + wave * 8 + j;
        const float4* wq4 = (const float4*)(Wq + (size_t)a * RNN);
        float acc = 0.f;
#pragma unroll
        for (int i = 0; i < 4; ++i) {
            float4 w4 = wq4[lane + 64 * i];
            float4 h4 = *(const float4*)(s_h + 4 * (lane + 64 * i));
            acc += w4.x * h4.x + w4.y * h4.y + w4.z * h4.z + w4.w * h4.w;
        }
#pragma unroll
        for (int off = 32; off > 0; off >>= 1) acc += __shfl_xor(acc, off, 64);
        if (lane == 0) pq[b * ATTN + a] = acc;
    }
}

// ---------------------------------------------------------------------------
// Kernel 2 (fused v2, thread-owns-t): wave = 32 t x 2 a-halves.
//   conv in registers (no handoff) -> a-half energy (Wloc via LDS broadcast)
//   -> 1 shuffle combine -> 5-shuffle wave softmax -> fused ctx partial.
// One barrier total (after staging). grid = B*16 = 1024, block = 256.
// ---------------------------------------------------------------------------
__global__ __launch_bounds__(256) void fused2_kernel(
    const float* __restrict__ pm,     // [B][T][ATTN]
    const float* __restrict__ awc,    // [B][2][T]
    const float* __restrict__ mem,    // [B][T][EMB]
    const unsigned char* __restrict__ mask,  // [B][T]
    const float* __restrict__ pq,     // [B][ATTN]
    const float* __restrict__ Wconv,  // [NF][2][KS]
    const float* __restrict__ Wloc,   // [ATTN][NF]
    const float* __restrict__ Wv,     // [ATTN]
    float* __restrict__ wp,           // [B][T] unnormalized exp
    float* __restrict__ ms,           // [B][NCH][2]
    float* __restrict__ cp)           // [B][NCH][EMB]
{
    int b = blockIdx.x >> 4;
    int blk = blockIdx.x & 15;
    int t0b = blk * TCHK_BLK;
    int tid = threadIdx.x;
    int w = tid >> 6;
    int l = tid & 63;
    int tpair = l >> 1;          // 0..31: t within wave
    int ah = l & 1;              // a-half: 0 -> a in [0,64), 1 -> [64,128)
    int t_local = w * TCHK_W + tpair;
    int tg = t0b + t_local;
    int ch = blk * 4 + w;        // global chunk id within b
    int t0w = t0b + w * TCHK_W;

    __shared__ float s_awc[2][TCHK_BLK + 2 * PADW + 2];  // 2 x 160
    __shared__ float s_wl[ATTN * NF];                    // 16 KB, [a][f]
    __shared__ float s_pq[ATTN];
    __shared__ float s_wv[ATTN];
    __shared__ float s_p[4][TCHK_W];

    // ---- stage: awc window, Wloc, pq, Wv ----
    for (int i = tid; i < 2 * (TCHK_BLK + 2 * PADW); i += 256) {
        int c = i / (TCHK_BLK + 2 * PADW);
        int j = i % (TCHK_BLK + 2 * PADW);
        int tgj = t0b - PADW + j;
        s_awc[c][j] = (tgj >= 0 && tgj < TT) ? awc[((size_t)b * 2 + c) * TT + tgj] : 0.f;
    }
#pragma unroll
    for (int i = 0; i < 4; ++i)
        ((float4*)s_wl)[tid + 256 * i] = ((const float4*)Wloc)[tid + 256 * i];
    if (tid < ATTN) {
        s_pq[tid] = pq[b * ATTN + tid];
        s_wv[tid] = Wv[tid];
    }
    __syncthreads();  // the only barrier

    // ---- conv for this thread's t: c_[32] in registers, 2 channel passes ----
    float c_[NF];
    {
        float aw[KS];
#pragma unroll
        for (int k = 0; k < KS; ++k) aw[k] = s_awc[0][t_local + k];
#pragma unroll
        for (int f = 0; f < NF; ++f) {
            float acc = 0.f;
#pragma unroll
            for (int k = 0; k < KS; ++k)
                acc += aw[k] * Wconv[(f * 2 + 0) * KS + k];  // uniform -> s_load
            c_[f] = acc;
        }
#pragma unroll
        for (int k = 0; k < KS; ++k) aw[k] = s_awc[1][t_local + k];
#pragma unroll
        for (int f = 0; f < NF; ++f) {
            float acc = c_[f];
#pragma unroll
            for (int k = 0; k < KS; ++k)
                acc += aw[k] * Wconv[(f * 2 + 1) * KS + k];
            c_[f] = acc;
        }
    }

    // ---- energy over this lane's a-half ----
    int a0 = ah * 64;
    const float4* pm4 = (const float4*)(pm + ((size_t)b * TT + tg) * ATTN + a0);
    float epart = 0.f;

    auto enA = [&](int a_rel, float pmc) {
        int a = a0 + a_rel;
        const float4* wl4 = (const float4*)&s_wl[a << 5];  // 2-addr broadcast: free
        float v = s_pq[a] + pmc;
#pragma unroll
        for (int f4 = 0; f4 < 8; ++f4) {
            float4 wq = wl4[f4];
            v += c_[f4 * 4 + 0] * wq.x + c_[f4 * 4 + 1] * wq.y +
                 c_[f4 * 4 + 2] * wq.z + c_[f4 * 4 + 3] * wq.w;
        }
        epart += s_wv[a] * fast_tanh(v);
    };

#pragma unroll
    for (int bt = 0; bt < 4; ++bt) {  // 16 a per batch; 64B/thread line-batched
        float4 q0 = pm4[bt * 4 + 0];
        float4 q1 = pm4[bt * 4 + 1];
        float4 q2 = pm4[bt * 4 + 2];
        float4 q3 = pm4[bt * 4 + 3];
        enA(bt * 16 + 0,  q0.x); enA(bt * 16 + 1,  q0.y);
        enA(bt * 16 + 2,  q0.z); enA(bt * 16 + 3,  q0.w);
        enA(bt * 16 + 4,  q1.x); enA(bt * 16 + 5,  q1.y);
        enA(bt * 16 + 6,  q1.z); enA(bt * 16 + 7,  q1.w);
        enA(bt * 16 + 8,  q2.x); enA(bt * 16 + 9,  q2.y);
        enA(bt * 16 + 10, q2.z); enA(bt * 16 + 11, q2.w);
        enA(bt * 16 + 12, q3.x); enA(bt * 16 + 13, q3.y);
        enA(bt * 16 + 14, q3.z); enA(bt * 16 + 15, q3.w);
    }

    // combine a-halves (pair lanes hold identical e after this)
    float e = epart + __shfl_xor(epart, 1, 64);
    if (mask[(size_t)b * TT + tg] != 0) e = -1e30f;

    // wave softmax over 32 t (values duplicated per pair; offs 2..32 reduce
    // exactly one copy of each t per parity class)
    float m = e;
#pragma unroll
    for (int off = 2; off < 64; off <<= 1) m = fmaxf(m, __shfl_xor(m, off, 64));
    float p = __expf(e - m);
    float s = p;
#pragma unroll
    for (int off = 2; off < 64; off <<= 1) s += __shfl_xor(s, off, 64);

    if (l == 0) {
        ms[((size_t)b * NCH + ch) * 2 + 0] = m;
        ms[((size_t)b * NCH + ch) * 2 + 1] = s;
    }
    if (ah == 0) {
        wp[(size_t)b * TT + tg] = p;
        s_p[w][tpair] = p;  // within-wave exchange; lgkmcnt ordering suffices
    }

    // ---- fused ctx partial over wave's 32 t: lane owns emb quads l, l+64 ----
    float4 A0 = {0.f, 0.f, 0.f, 0.f}, A1 = {0.f, 0.f, 0.f, 0.f};
    const float4* m4 = (const float4*)(mem + ((size_t)b * TT + t0w) * EMB);
#pragma unroll 8
    for (int i = 0; i < TCHK_W; ++i) {
        float pv = s_p[w][i];
        float4 v0 = m4[(size_t)i * (EMB / 4) + l];
        float4 v1 = m4[(size_t)i * (EMB / 4) + 64 + l];
        A0.x += pv * v0.x; A0.y += pv * v0.y; A0.z += pv * v0.z; A0.w += pv * v0.w;
        A1.x += pv * v1.x; A1.y += pv * v1.y; A1.z += pv * v1.z; A1.w += pv * v1.w;
    }
    float4* cp4 = (float4*)(cp + ((size_t)b * NCH + ch) * EMB);
    cp4[l] = A0;
    cp4[64 + l] = A1;
}

// ---------------------------------------------------------------------------
// Kernel 3: combine. grid = B, block = 256.
// ---------------------------------------------------------------------------
__global__ __launch_bounds__(256) void combine_kernel(
    const float* __restrict__ wp, const float* __restrict__ ms,
    const float* __restrict__ cp, float* __restrict__ ctx,
    float* __restrict__ wts) {
    int b = blockIdx.x;
    int tid = threadIdx.x;
    __shared__ float s_m[NCH], s_s[NCH], s_scale[NCH];
    if (tid < NCH) {
        s_m[tid] = ms[((size_t)b * NCH + tid) * 2 + 0];
        s_s[tid] = ms[((size_t)b * NCH + tid) * 2 + 1];
    }
    __syncthreads();
    float M = -1e30f;
#pragma unroll 8
    for (int c = 0; c < NCH; ++c) M = fmaxf(M, s_m[c]);
    float S = 0.f;
#pragma unroll 8
    for (int c = 0; c < NCH; ++c) S += s_s[c] * __expf(s_m[c] - M);
    float invS = 1.f / S;
    if (tid < NCH) s_scale[tid] = __expf(s_m[tid] - M) * invS;
    __syncthreads();

    {
        float2 acc = {0.f, 0.f};
        const float2* cp2 = (const float2*)(cp + (size_t)b * NCH * EMB);
#pragma unroll 8
        for (int c = 0; c < NCH; ++c) {
            float sc = s_scale[c];
            float2 v = cp2[(size_t)c * (EMB / 2) + tid];
            acc.x += sc * v.x;
            acc.y += sc * v.y;
        }
        ((float2*)(ctx + (size_t)b * EMB))[tid] = acc;
    }
#pragma unroll
    for (int i = 0; i < 8; ++i) {
        int t = i * 256 + tid;
        wts[(size_t)b * TT + t] = wp[(size_t)b * TT + t] * s_scale[t >> 5];
    }
}

// ---------------------------------------------------------------------------
extern "C" void kernel_launch(void* const* d_in, const int* in_sizes, int n_in,
                              void* d_out, int out_size, void* d_ws, size_t ws_size,
                              hipStream_t stream) {
    const float* h    = (const float*)d_in[0];
    const float* mem  = (const float*)d_in[1];
    const float* pmem = (const float*)d_in[2];
    const float* awc  = (const float*)d_in[3];
    const unsigned char* mask = (const unsigned char*)d_in[4];
    const float* Wq   = (const float*)d_in[5];
    const float* Wcv  = (const float*)d_in[6];
    const float* Wloc = (const float*)d_in[7];
    const float* Wv   = (const float*)d_in[8];

    float* out = (float*)d_out;
    float* ctx = out;             // [B][EMB]
    float* wts = out + BB * EMB;  // [B][T]

    float* ws = (float*)d_ws;
    float* pq = ws;                 // [B][ATTN]
    float* wp = pq + BB * ATTN;     // [B][T]
    float* ms = wp + BB * TT;       // [B][NCH][2]
    float* cp = ms + BB * NCH * 2;  // [B][NCH][EMB]

    pq_kernel<<<BB * 4, 256, 0, stream>>>(h, Wq, pq);
    fused2_kernel<<<BB * 16, 256, 0, stream>>>(pmem, awc, mem, mask, pq, Wcv,
                                               Wloc, Wv, wp, ms, cp);
    combine_kernel<<<BB, 256, 0, stream>>>(wp, ms, cp, ctx, wts);
}